// Round 1
// baseline (690.666 us; speedup 1.0000x reference)
//
#include <hip/hip_runtime.h>
#include <math.h>

// ---------------------------------------------------------------------------
// HeteroGNN forward, fp32.
// Decomposition:
//   Wf (192 x F) = [ M = 0.5*(Wul0@Wd0 + Wul1@Wd1) ; S0 = 0.5*Wur0@Ws0 ; S1 = 0.5*Wur1@Ws1 ]
//   GEMM: [h | P0 | P1] = x @ Wf^T      (h = base term, P_i = per-type projected src feats)
//   scatter: h[dst] += P_i[src] * inv_cnt_i[dst]   (mean-agg folded via linearity)
//   BN(training, eps=1, biased var) + LeakyReLU(0.01)
//   output: [x[src]||x[dst]] per edge, e0 rows then e1 rows.
// ---------------------------------------------------------------------------

#define H 64

__global__ void fusew_kernel(const float* __restrict__ Wd0, const float* __restrict__ Ws0,
                             const float* __restrict__ Wu0,
                             const float* __restrict__ Wd1, const float* __restrict__ Ws1,
                             const float* __restrict__ Wu1,
                             float* __restrict__ Wf, int K) {
  int gid = blockIdx.x * blockDim.x + threadIdx.x;
  int total = 192 * K;
  if (gid >= total) return;
  int i = gid / K, j = gid - i * K;
  float s = 0.f;
  if (i < 64) {
#pragma unroll 4
    for (int k = 0; k < 64; ++k)
      s += Wu0[i * 128 + k] * Wd0[k * K + j] + Wu1[i * 128 + k] * Wd1[k * K + j];
  } else if (i < 128) {
    int ii = i - 64;
#pragma unroll 4
    for (int k = 0; k < 64; ++k) s += Wu0[ii * 128 + 64 + k] * Ws0[k * K + j];
  } else {
    int ii = i - 128;
#pragma unroll 4
    for (int k = 0; k < 64; ++k) s += Wu1[ii * 128 + 64 + k] * Ws1[k * K + j];
  }
  Wf[gid] = 0.5f * s;
}

__global__ void count_kernel(const int* __restrict__ dst, float* __restrict__ cnt, int E) {
  int gid = blockIdx.x * blockDim.x + threadIdx.x;
  if (gid < E) atomicAdd(&cnt[dst[gid]], 1.0f);
}

__global__ void inv_kernel(float* __restrict__ cnt, int n) {
  int gid = blockIdx.x * blockDim.x + threadIdx.x;
  if (gid < n) cnt[gid] = 1.0f / fmaxf(cnt[gid], 1.0f);
}

// out[h|P0|P1] = x[N,K] @ Wf[192,K]^T ; 16 rows/block, 256 threads.
__global__ __launch_bounds__(256) void matmul_kernel(const float* __restrict__ x,
                                                     const float* __restrict__ Wf,
                                                     float* __restrict__ h,
                                                     float* __restrict__ P0,
                                                     float* __restrict__ P1, int N, int K) {
  __shared__ float ws[32 * 193];  // [k][r] transposed, pad 193 -> conflict-free
  __shared__ float xs[16 * 32];
  int tid = threadIdx.x;
  int c = tid & 63;    // output col within 64
  int rq = tid >> 6;   // wave id 0..3 -> rows rq*4..rq*4+3
  int row0 = blockIdx.x * 16;
  float acc0[4] = {0, 0, 0, 0}, acc1[4] = {0, 0, 0, 0}, acc2[4] = {0, 0, 0, 0};
  for (int k0 = 0; k0 < K; k0 += 32) {
    for (int i = tid; i < 192 * 32; i += 256) {
      int r = i >> 5, k = i & 31;
      ws[k * 193 + r] = Wf[r * K + k0 + k];
    }
    if (tid < 128) {
      int r = tid >> 3, q = tid & 7;
      int grow = row0 + r;
      float4 v = make_float4(0.f, 0.f, 0.f, 0.f);
      if (grow < N) v = *(const float4*)&x[(size_t)grow * K + k0 + q * 4];
      *(float4*)&xs[r * 32 + q * 4] = v;
    }
    __syncthreads();
#pragma unroll
    for (int k = 0; k < 32; ++k) {
      float w0 = ws[k * 193 + c];
      float w1 = ws[k * 193 + 64 + c];
      float w2 = ws[k * 193 + 128 + c];
#pragma unroll
      for (int r = 0; r < 4; ++r) {
        float xv = xs[(rq * 4 + r) * 32 + k];  // wave-uniform -> LDS broadcast
        acc0[r] = fmaf(w0, xv, acc0[r]);
        acc1[r] = fmaf(w1, xv, acc1[r]);
        acc2[r] = fmaf(w2, xv, acc2[r]);
      }
    }
    __syncthreads();
  }
#pragma unroll
  for (int r = 0; r < 4; ++r) {
    int row = row0 + rq * 4 + r;
    if (row < N) {
      h[(size_t)row * 64 + c] = acc0[r];
      P0[(size_t)row * 64 + c] = acc1[r];
      P1[(size_t)row * 64 + c] = acc2[r];
    }
  }
}

// h[dst] += P[src] * inv[dst]; one wave per edge (64 channels).
__global__ void scatter_kernel(const float* __restrict__ P, const int* __restrict__ src,
                               const int* __restrict__ dst, const float* __restrict__ inv,
                               float* __restrict__ h, int E) {
  int gid = blockIdx.x * blockDim.x + threadIdx.x;
  int e = gid >> 6;
  if (e >= E) return;
  int c = gid & 63;
  int s = src[e], d = dst[e];
  atomicAdd(&h[(size_t)d * 64 + c], P[(size_t)s * 64 + c] * inv[d]);
}

__global__ __launch_bounds__(256) void bnstats_kernel(const float* __restrict__ h,
                                                      float* __restrict__ stats, int N) {
  int tid = threadIdx.x;
  int c = tid & 63;
  int part = tid >> 6;  // 0..3
  float s = 0.f, s2 = 0.f;
  for (int r = blockIdx.x * 4 + part; r < N; r += gridDim.x * 4) {
    float v = h[(size_t)r * 64 + c];
    s += v;
    s2 += v * v;
  }
  __shared__ float red[512];
  red[tid] = s;
  red[256 + tid] = s2;
  __syncthreads();
  if (part == 0) {
    s = red[c] + red[64 + c] + red[128 + c] + red[192 + c];
    s2 = red[256 + c] + red[256 + 64 + c] + red[256 + 128 + c] + red[256 + 192 + c];
    atomicAdd(&stats[c], s);
    atomicAdd(&stats[64 + c], s2);
  }
}

// stats[0:64]=sum, [64:128]=sumsq -> [128:192]=scale a, [192:256]=shift bb
__global__ void bnfinal_kernel(float* __restrict__ stats, const float* __restrict__ g,
                               const float* __restrict__ b, float invN) {
  int c = threadIdx.x;
  if (c >= 64) return;
  float m = stats[c] * invN;
  float v = stats[64 + c] * invN - m * m;
  float a = g[c] * rsqrtf(v + 1.0f);
  stats[128 + c] = a;
  stats[192 + c] = b[c] - m * a;
}

__global__ void bnapply_kernel(const float* __restrict__ h, const float* __restrict__ stats,
                               float* __restrict__ xo, int N) {
  int gid = blockIdx.x * blockDim.x + threadIdx.x;
  if (gid >= N * 16) return;
  float4 v = ((const float4*)h)[gid];
  int c = (gid & 15) * 4;
  const float* a = stats + 128;
  const float* bb = stats + 192;
  float4 o;
  o.x = fmaf(a[c + 0], v.x, bb[c + 0]);
  o.y = fmaf(a[c + 1], v.y, bb[c + 1]);
  o.z = fmaf(a[c + 2], v.z, bb[c + 2]);
  o.w = fmaf(a[c + 3], v.w, bb[c + 3]);
  o.x = o.x > 0.f ? o.x : 0.01f * o.x;
  o.y = o.y > 0.f ? o.y : 0.01f * o.y;
  o.z = o.z > 0.f ? o.z : 0.01f * o.z;
  o.w = o.w > 0.f ? o.w : 0.01f * o.w;
  ((float4*)xo)[gid] = o;
}

// out[row, 0:64]=x[src], out[row, 64:128]=x[dst]; rows 0..E-1 type0, E..2E-1 type1.
__global__ void gather_kernel(const float* __restrict__ x, const int* __restrict__ src0,
                              const int* __restrict__ dst0, const int* __restrict__ src1,
                              const int* __restrict__ dst1, float* __restrict__ out, int E) {
  int gid = blockIdx.x * blockDim.x + threadIdx.x;  // one float4 each
  int total = 2 * E * 32;
  if (gid >= total) return;
  int row = gid >> 5, q = gid & 31;
  int e, s, d;
  if (row < E) {
    e = row; s = src0[e]; d = dst0[e];
  } else {
    e = row - E; s = src1[e]; d = dst1[e];
  }
  int node = (q < 16) ? s : d;
  int qq = q & 15;
  float4 v = *(const float4*)&x[(size_t)node * 64 + qq * 4];
  ((float4*)out)[gid] = v;
}

extern "C" void kernel_launch(void* const* d_in, const int* in_sizes, int n_in,
                              void* d_out, int out_size, void* d_ws, size_t ws_size,
                              hipStream_t stream) {
  const float* x0 = (const float*)d_in[0];
  const int* ei0 = (const int*)d_in[1];
  const int* ei1 = (const int*)d_in[2];
  const float* l1t0_Wd = (const float*)d_in[3];
  const float* l1t0_Ws = (const float*)d_in[4];
  const float* l1t0_Wu = (const float*)d_in[5];
  const float* l1t1_Wd = (const float*)d_in[6];
  const float* l1t1_Ws = (const float*)d_in[7];
  const float* l1t1_Wu = (const float*)d_in[8];
  const float* l2t0_Wd = (const float*)d_in[9];
  const float* l2t0_Ws = (const float*)d_in[10];
  const float* l2t0_Wu = (const float*)d_in[11];
  const float* l2t1_Wd = (const float*)d_in[12];
  const float* l2t1_Ws = (const float*)d_in[13];
  const float* l2t1_Wu = (const float*)d_in[14];
  const float* bn1_g = (const float*)d_in[15];
  const float* bn1_b = (const float*)d_in[16];
  const float* bn2_g = (const float*)d_in[17];
  const float* bn2_b = (const float*)d_in[18];

  const int N = in_sizes[0] / 128;
  const int E = in_sizes[1] / 2;
  const int* src0 = ei0, *dst0 = ei0 + E;
  const int* src1 = ei1, *dst1 = ei1 + E;

  float* ws = (float*)d_ws;
  size_t off = 0;
  float* Wf1 = ws + off; off += 192 * 128;
  float* Wf2 = ws + off; off += 192 * 64;
  float* inv0 = ws + off; off += N;
  float* inv1 = ws + off; off += N;
  float* stats = ws + off; off += 256;
  off = (off + 3) & ~(size_t)3;
  float* h = ws + off; off += (size_t)N * 64;
  float* P0 = ws + off; off += (size_t)N * 64;
  float* P1 = ws + off; off += (size_t)N * 64;
  float* xc = ws + off; off += (size_t)N * 64;

  const float invN = 1.0f / (float)N;

  // --- fused weights ---
  fusew_kernel<<<(192 * 128 + 255) / 256, 256, 0, stream>>>(
      l1t0_Wd, l1t0_Ws, l1t0_Wu, l1t1_Wd, l1t1_Ws, l1t1_Wu, Wf1, 128);
  fusew_kernel<<<(192 * 64 + 255) / 256, 256, 0, stream>>>(
      l2t0_Wd, l2t0_Ws, l2t0_Wu, l2t1_Wd, l2t1_Ws, l2t1_Wu, Wf2, 64);

  // --- edge counts -> 1/max(cnt,1) (shared by both layers) ---
  hipMemsetAsync(inv0, 0, (size_t)N * sizeof(float), stream);
  hipMemsetAsync(inv1, 0, (size_t)N * sizeof(float), stream);
  count_kernel<<<(E + 255) / 256, 256, 0, stream>>>(dst0, inv0, E);
  count_kernel<<<(E + 255) / 256, 256, 0, stream>>>(dst1, inv1, E);
  inv_kernel<<<(N + 255) / 256, 256, 0, stream>>>(inv0, N);
  inv_kernel<<<(N + 255) / 256, 256, 0, stream>>>(inv1, N);

  const int scatterGrid = (E * 64 + 255) / 256;

  // --- layer 1 ---
  matmul_kernel<<<(N + 15) / 16, 256, 0, stream>>>(x0, Wf1, h, P0, P1, N, 128);
  scatter_kernel<<<scatterGrid, 256, 0, stream>>>(P0, src0, dst0, inv0, h, E);
  scatter_kernel<<<scatterGrid, 256, 0, stream>>>(P1, src1, dst1, inv1, h, E);
  hipMemsetAsync(stats, 0, 256 * sizeof(float), stream);
  bnstats_kernel<<<256, 256, 0, stream>>>(h, stats, N);
  bnfinal_kernel<<<1, 64, 0, stream>>>(stats, bn1_g, bn1_b, invN);
  bnapply_kernel<<<(N * 16 + 255) / 256, 256, 0, stream>>>(h, stats, xc, N);

  // --- layer 2 ---
  matmul_kernel<<<(N + 15) / 16, 256, 0, stream>>>(xc, Wf2, h, P0, P1, N, 64);
  scatter_kernel<<<scatterGrid, 256, 0, stream>>>(P0, src0, dst0, inv0, h, E);
  scatter_kernel<<<scatterGrid, 256, 0, stream>>>(P1, src1, dst1, inv1, h, E);
  hipMemsetAsync(stats, 0, 256 * sizeof(float), stream);
  bnstats_kernel<<<256, 256, 0, stream>>>(h, stats, N);
  bnfinal_kernel<<<1, 64, 0, stream>>>(stats, bn2_g, bn2_b, invN);
  bnapply_kernel<<<(N * 16 + 255) / 256, 256, 0, stream>>>(h, stats, xc, N);

  // --- edge embedding gather ---
  gather_kernel<<<(2 * E * 32 + 255) / 256, 256, 0, stream>>>(
      xc, src0, dst0, src1, dst1, (float*)d_out, E);
}

// Round 2
// 567.216 us; speedup vs baseline: 1.2176x; 1.2176x over previous
//
#include <hip/hip_runtime.h>
#include <math.h>

// ---------------------------------------------------------------------------
// HeteroGNN forward, fp32, CSR-based (no float atomics).
//   Wf (192 x F) = [ M = 0.5*(Wul0@Wd0 + Wul1@Wd1) ; S0 = 0.5*Wur0@Ws0 ; S1 = 0.5*Wur1@Ws1 ]
//   GEMM: [h | P0 | P1] = x @ Wf^T
//   CSR per edge type (built once, reused by both layers)
//   agg: h[d] += (1/cnt0[d]) * sum_{e in csr0[d]} P0[src] + (1/cnt1[d]) * sum ...
//   BN(training, eps=1, biased var) + LeakyReLU(0.01); layer1's BN-apply fused
//   into layer2's GEMM staging load.
//   output: [x[src]||x[dst]] per edge, e0 rows then e1 rows (nontemporal).
// ---------------------------------------------------------------------------

typedef float f32x4 __attribute__((ext_vector_type(4)));

__global__ void fusew_kernel(const float* __restrict__ Wd0, const float* __restrict__ Ws0,
                             const float* __restrict__ Wu0,
                             const float* __restrict__ Wd1, const float* __restrict__ Ws1,
                             const float* __restrict__ Wu1,
                             float* __restrict__ Wf, int K) {
  int gid = blockIdx.x * blockDim.x + threadIdx.x;
  int total = 192 * K;
  if (gid >= total) return;
  int i = gid / K, j = gid - i * K;
  float s = 0.f;
  if (i < 64) {
#pragma unroll 4
    for (int k = 0; k < 64; ++k)
      s += Wu0[i * 128 + k] * Wd0[k * K + j] + Wu1[i * 128 + k] * Wd1[k * K + j];
  } else if (i < 128) {
    int ii = i - 64;
#pragma unroll 4
    for (int k = 0; k < 64; ++k) s += Wu0[ii * 128 + 64 + k] * Ws0[k * K + j];
  } else {
    int ii = i - 128;
#pragma unroll 4
    for (int k = 0; k < 64; ++k) s += Wu1[ii * 128 + 64 + k] * Ws1[k * K + j];
  }
  Wf[gid] = 0.5f * s;
}

__global__ void count_kernel(const int* __restrict__ dst, int* __restrict__ cnt, int E) {
  int gid = blockIdx.x * blockDim.x + threadIdx.x;
  if (gid < E) atomicAdd(&cnt[dst[gid]], 1);
}

// 2 blocks x 1024 threads: block 0 scans cnt0->base0, block 1 cnt1->base1.
__global__ __launch_bounds__(1024) void scan_kernel(const int* __restrict__ cnt0,
                                                    const int* __restrict__ cnt1,
                                                    int* __restrict__ base0,
                                                    int* __restrict__ base1, int N) {
  const int nt = 1024;
  __shared__ int lds[1024];
  const int* cnt = blockIdx.x == 0 ? cnt0 : cnt1;
  int* base = blockIdx.x == 0 ? base0 : base1;
  int t = threadIdx.x;
  int chunk = (N + nt - 1) / nt;
  int s = t * chunk;
  int e = min(N, s + chunk);
  int sum = 0;
  for (int i = s; i < e; ++i) sum += cnt[i];
  lds[t] = sum;
  __syncthreads();
  for (int off = 1; off < nt; off <<= 1) {
    int v = lds[t];
    if (t >= off) v += lds[t - off];
    __syncthreads();
    lds[t] = v;
    __syncthreads();
  }
  int run = lds[t] - sum;  // exclusive prefix of this thread's chunk
  for (int i = s; i < e; ++i) {
    base[i] = run;
    run += cnt[i];
  }
  if (t == nt - 1) base[N] = lds[nt - 1];
}

// bucket fill; consumes cnt down to zero (cnt re-zeroed by memset next call).
__global__ void fill_kernel(const int* __restrict__ src, const int* __restrict__ dst,
                            const int* __restrict__ base, int* __restrict__ cnt,
                            int* __restrict__ csr, int E) {
  int e = blockIdx.x * blockDim.x + threadIdx.x;
  if (e >= E) return;
  int d = dst[e];
  int p = atomicSub(&cnt[d], 1) - 1;
  csr[base[d] + p] = src[e];
}

// [h|P0|P1] = x[N,K] @ Wf[192,K]^T.  32 rows/block, 256 threads, 24 acc/thread.
// If stats != nullptr, applies y = a[col]*x + b[col]; leaky(0.01) to staged x
// (fuses previous layer's BN-apply + activation).
__global__ __launch_bounds__(256) void matmul_kernel(const float* __restrict__ x,
                                                     const float* __restrict__ Wf,
                                                     const float* __restrict__ stats,
                                                     float* __restrict__ h,
                                                     float* __restrict__ P0,
                                                     float* __restrict__ P1, int N, int K) {
  __shared__ float ws[32 * 193];  // [k][row], pad 193
  __shared__ float xs[32 * 32];   // [k][r]
  int tid = threadIdx.x;
  int c = tid & 63;   // output col within each 64-block (lane id)
  int rq = tid >> 6;  // wave id 0..3 -> rows rq*8 .. rq*8+7
  int row0 = blockIdx.x * 32;
  float acc0[8] = {0}, acc1[8] = {0}, acc2[8] = {0};
  const float* sa = stats ? stats + 128 : nullptr;
  const float* sb = stats ? stats + 192 : nullptr;
  for (int k0 = 0; k0 < K; k0 += 32) {
    // stage weights: 192 rows x 32 cols (1536 float4)
    for (int i = tid; i < 1536; i += 256) {
      int q = i / 192;       // col group 0..7
      int r = i - q * 192;   // row 0..191
      f32x4 v = *(const f32x4*)&Wf[(size_t)r * K + k0 + q * 4];
      ws[(q * 4 + 0) * 193 + r] = v.x;
      ws[(q * 4 + 1) * 193 + r] = v.y;
      ws[(q * 4 + 2) * 193 + r] = v.z;
      ws[(q * 4 + 3) * 193 + r] = v.w;
    }
    // stage x: 32 rows x 32 cols (256 float4, 1/thread), transposed
    {
      int r = tid & 31, q = tid >> 5;  // q 0..7
      int grow = row0 + r;
      int col = k0 + q * 4;
      f32x4 v = {0.f, 0.f, 0.f, 0.f};
      if (grow < N) v = *(const f32x4*)&x[(size_t)grow * K + col];
      if (stats) {
#pragma unroll
        for (int j = 0; j < 4; ++j) {
          float o = fmaf(sa[col + j], v[j], sb[col + j]);
          v[j] = fmaxf(o, 0.01f * o);
        }
      }
      xs[(q * 4 + 0) * 32 + r] = v.x;
      xs[(q * 4 + 1) * 32 + r] = v.y;
      xs[(q * 4 + 2) * 32 + r] = v.z;
      xs[(q * 4 + 3) * 32 + r] = v.w;
    }
    __syncthreads();
#pragma unroll
    for (int k = 0; k < 32; ++k) {
      float w0 = ws[k * 193 + c];
      float w1 = ws[k * 193 + 64 + c];
      float w2 = ws[k * 193 + 128 + c];
      float xv[8];
      *(f32x4*)&xv[0] = *(const f32x4*)&xs[k * 32 + rq * 8];      // wave-uniform
      *(f32x4*)&xv[4] = *(const f32x4*)&xs[k * 32 + rq * 8 + 4];  // -> broadcast
#pragma unroll
      for (int r = 0; r < 8; ++r) {
        acc0[r] = fmaf(w0, xv[r], acc0[r]);
        acc1[r] = fmaf(w1, xv[r], acc1[r]);
        acc2[r] = fmaf(w2, xv[r], acc2[r]);
      }
    }
    __syncthreads();
  }
#pragma unroll
  for (int r = 0; r < 8; ++r) {
    int row = row0 + rq * 8 + r;
    if (row < N) {
      h[(size_t)row * 64 + c] = acc0[r];
      P0[(size_t)row * 64 + c] = acc1[r];
      P1[(size_t)row * 64 + c] = acc2[r];
    }
  }
}

// one wave per dst node; mean-agg both edge types, accumulate into h.
__global__ void agg_kernel(float* __restrict__ h, const float* __restrict__ P0,
                           const float* __restrict__ P1, const int* __restrict__ csr0,
                           const int* __restrict__ base0, const int* __restrict__ csr1,
                           const int* __restrict__ base1, int N) {
  int gid = blockIdx.x * blockDim.x + threadIdx.x;
  int w = gid >> 6, c = gid & 63;
  if (w >= N) return;
  int b0 = base0[w], e0 = base0[w + 1];
  float acc0 = 0.f;
  for (int i = b0; i < e0; ++i) acc0 += P0[(size_t)csr0[i] * 64 + c];
  int b1 = base1[w], e1 = base1[w + 1];
  float acc1 = 0.f;
  for (int i = b1; i < e1; ++i) acc1 += P1[(size_t)csr1[i] * 64 + c];
  float i0 = 1.0f / fmaxf((float)(e0 - b0), 1.0f);
  float i1 = 1.0f / fmaxf((float)(e1 - b1), 1.0f);
  h[(size_t)w * 64 + c] += acc0 * i0 + acc1 * i1;
}

__global__ __launch_bounds__(256) void bnstats_kernel(const float* __restrict__ h,
                                                      float* __restrict__ stats, int N) {
  int tid = threadIdx.x;
  int c = tid & 63;
  int part = tid >> 6;  // 0..3
  float s = 0.f, s2 = 0.f;
  for (int r = blockIdx.x * 4 + part; r < N; r += gridDim.x * 4) {
    float v = h[(size_t)r * 64 + c];
    s += v;
    s2 += v * v;
  }
  __shared__ float red[512];
  red[tid] = s;
  red[256 + tid] = s2;
  __syncthreads();
  if (part == 0) {
    s = red[c] + red[64 + c] + red[128 + c] + red[192 + c];
    s2 = red[256 + c] + red[256 + 64 + c] + red[256 + 128 + c] + red[256 + 192 + c];
    atomicAdd(&stats[c], s);
    atomicAdd(&stats[64 + c], s2);
  }
}

__global__ void bnfinal_kernel(float* __restrict__ stats, const float* __restrict__ g,
                               const float* __restrict__ b, float invN) {
  int c = threadIdx.x;
  if (c >= 64) return;
  float m = stats[c] * invN;
  float v = stats[64 + c] * invN - m * m;
  float a = g[c] * rsqrtf(v + 1.0f);
  stats[128 + c] = a;
  stats[192 + c] = b[c] - m * a;
}

__global__ void bnapply_kernel(const float* __restrict__ h, const float* __restrict__ stats,
                               float* __restrict__ xo, int N) {
  int gid = blockIdx.x * blockDim.x + threadIdx.x;
  if (gid >= N * 16) return;
  f32x4 v = ((const f32x4*)h)[gid];
  int c = (gid & 15) * 4;
  const float* a = stats + 128;
  const float* bb = stats + 192;
  f32x4 o;
#pragma unroll
  for (int j = 0; j < 4; ++j) {
    float t = fmaf(a[c + j], v[j], bb[c + j]);
    o[j] = fmaxf(t, 0.01f * t);
  }
  ((f32x4*)xo)[gid] = o;
}

// out[row, 0:64]=x[src], out[row, 64:128]=x[dst]; rows 0..E-1 type0, E..2E-1 type1.
__global__ void gather_kernel(const float* __restrict__ x, const int* __restrict__ src0,
                              const int* __restrict__ dst0, const int* __restrict__ src1,
                              const int* __restrict__ dst1, float* __restrict__ out, int E) {
  int gid = blockIdx.x * blockDim.x + threadIdx.x;  // one float4 each
  int total = 2 * E * 32;
  if (gid >= total) return;
  int row = gid >> 5, q = gid & 31;
  int e, s, d;
  if (row < E) {
    e = row; s = src0[e]; d = dst0[e];
  } else {
    e = row - E; s = src1[e]; d = dst1[e];
  }
  int node = (q < 16) ? s : d;
  int qq = q & 15;
  f32x4 v = *(const f32x4*)&x[(size_t)node * 64 + qq * 4];
  __builtin_nontemporal_store(v, (f32x4*)out + gid);
}

extern "C" void kernel_launch(void* const* d_in, const int* in_sizes, int n_in,
                              void* d_out, int out_size, void* d_ws, size_t ws_size,
                              hipStream_t stream) {
  const float* x0 = (const float*)d_in[0];
  const int* ei0 = (const int*)d_in[1];
  const int* ei1 = (const int*)d_in[2];
  const float* l1t0_Wd = (const float*)d_in[3];
  const float* l1t0_Ws = (const float*)d_in[4];
  const float* l1t0_Wu = (const float*)d_in[5];
  const float* l1t1_Wd = (const float*)d_in[6];
  const float* l1t1_Ws = (const float*)d_in[7];
  const float* l1t1_Wu = (const float*)d_in[8];
  const float* l2t0_Wd = (const float*)d_in[9];
  const float* l2t0_Ws = (const float*)d_in[10];
  const float* l2t0_Wu = (const float*)d_in[11];
  const float* l2t1_Wd = (const float*)d_in[12];
  const float* l2t1_Ws = (const float*)d_in[13];
  const float* l2t1_Wu = (const float*)d_in[14];
  const float* bn1_g = (const float*)d_in[15];
  const float* bn1_b = (const float*)d_in[16];
  const float* bn2_g = (const float*)d_in[17];
  const float* bn2_b = (const float*)d_in[18];

  const int N = in_sizes[0] / 128;
  const int E = in_sizes[1] / 2;
  const int *src0 = ei0, *dst0 = ei0 + E;
  const int *src1 = ei1, *dst1 = ei1 + E;

  float* ws = (float*)d_ws;
  size_t off = 0;
  auto alloc = [&](size_t n) {
    float* p = ws + off;
    off += (n + 63) & ~(size_t)63;
    return p;
  };
  float* Wf1 = alloc(192 * 128);
  float* Wf2 = alloc(192 * 64);
  float* stats1 = alloc(256);
  float* stats2 = alloc(256);
  int* cnt0 = (int*)alloc(N);
  int* cnt1 = (int*)alloc(N);
  int* base0 = (int*)alloc(N + 1);
  int* base1 = (int*)alloc(N + 1);
  int* csr0 = (int*)alloc(E);
  int* csr1 = (int*)alloc(E);
  float* h = alloc((size_t)N * 64);
  float* P0 = alloc((size_t)N * 64);
  float* P1 = alloc((size_t)N * 64);
  float* h2 = alloc((size_t)N * 64);
  float* xc = alloc((size_t)N * 64);

  const float invN = 1.0f / (float)N;
  const int eg = (E + 255) / 256;

  // fused weights
  fusew_kernel<<<(192 * 128 + 255) / 256, 256, 0, stream>>>(
      l1t0_Wd, l1t0_Ws, l1t0_Wu, l1t1_Wd, l1t1_Ws, l1t1_Wu, Wf1, 128);
  fusew_kernel<<<(192 * 64 + 255) / 256, 256, 0, stream>>>(
      l2t0_Wd, l2t0_Ws, l2t0_Wu, l2t1_Wd, l2t1_Ws, l2t1_Wu, Wf2, 64);

  // CSR build (shared by both layers)
  hipMemsetAsync(cnt0, 0, (size_t)N * sizeof(int), stream);
  hipMemsetAsync(cnt1, 0, (size_t)N * sizeof(int), stream);
  count_kernel<<<eg, 256, 0, stream>>>(dst0, cnt0, E);
  count_kernel<<<eg, 256, 0, stream>>>(dst1, cnt1, E);
  scan_kernel<<<2, 1024, 0, stream>>>(cnt0, cnt1, base0, base1, N);
  fill_kernel<<<eg, 256, 0, stream>>>(src0, dst0, base0, cnt0, csr0, E);
  fill_kernel<<<eg, 256, 0, stream>>>(src1, dst1, base1, cnt1, csr1, E);

  const int aggGrid = (N * 64 + 255) / 256;
  const int mmGrid = (N + 31) / 32;

  // layer 1
  matmul_kernel<<<mmGrid, 256, 0, stream>>>(x0, Wf1, nullptr, h, P0, P1, N, 128);
  agg_kernel<<<aggGrid, 256, 0, stream>>>(h, P0, P1, csr0, base0, csr1, base1, N);
  hipMemsetAsync(stats1, 0, 256 * sizeof(float), stream);
  bnstats_kernel<<<256, 256, 0, stream>>>(h, stats1, N);
  bnfinal_kernel<<<1, 64, 0, stream>>>(stats1, bn1_g, bn1_b, invN);

  // layer 2 (BN1-apply + leaky fused into staging)
  matmul_kernel<<<mmGrid, 256, 0, stream>>>(h, Wf2, stats1, h2, P0, P1, N, 64);
  agg_kernel<<<aggGrid, 256, 0, stream>>>(h2, P0, P1, csr0, base0, csr1, base1, N);
  hipMemsetAsync(stats2, 0, 256 * sizeof(float), stream);
  bnstats_kernel<<<256, 256, 0, stream>>>(h2, stats2, N);
  bnfinal_kernel<<<1, 64, 0, stream>>>(stats2, bn2_g, bn2_b, invN);
  bnapply_kernel<<<(N * 16 + 255) / 256, 256, 0, stream>>>(h2, stats2, xc, N);

  // edge embedding gather
  gather_kernel<<<(2 * E * 32 + 255) / 256, 256, 0, stream>>>(
      xc, src0, dst0, src1, dst1, (float*)d_out, E);
}

// Round 3
// 464.258 us; speedup vs baseline: 1.4877x; 1.2218x over previous
//
#include <hip/hip_runtime.h>
#include <math.h>

// ---------------------------------------------------------------------------
// HeteroGNN forward. bf16 MFMA GEMM (B-in-registers, A from global, no LDS),
// bf16 projected features for CSR mean-agg, fp32 h/BN path, BN2 fused into
// the output gather.
//   Wf (192 x F) = [ 0.5*(Wul0@Wd0 + Wul1@Wd1) ; 0.5*Wur0@Ws0 ; 0.5*Wur1@Ws1 ]
//   [h | P0 | P1] = x @ Wf^T   (h fp32, P bf16)
//   h[d] += mean_{csr0[d]} P0[src] + mean_{csr1[d]} P1[src]
//   BN(train, eps=1, biased) + LeakyReLU(0.01)
// ---------------------------------------------------------------------------

typedef float f32x4 __attribute__((ext_vector_type(4)));
typedef float f32x2 __attribute__((ext_vector_type(2)));
typedef short bf16x8 __attribute__((ext_vector_type(8)));
typedef unsigned short u16x4 __attribute__((ext_vector_type(4)));

static __device__ __forceinline__ unsigned short f2bf(float f) {
  unsigned int u = __builtin_bit_cast(unsigned int, f);
  unsigned int r = (u + 0x7FFFu + ((u >> 16) & 1u)) >> 16;
  return (unsigned short)r;
}
static __device__ __forceinline__ float bfl(unsigned int u) {
  return __builtin_bit_cast(float, u << 16);
}
static __device__ __forceinline__ float bfh(unsigned int u) {
  return __builtin_bit_cast(float, u & 0xFFFF0000u);
}

__global__ void zero_kernel(int* __restrict__ cnt0, int* __restrict__ cnt1,
                            float* __restrict__ s1, float* __restrict__ s2, int N) {
  int g = blockIdx.x * 256 + threadIdx.x;
  if (g < N) { cnt0[g] = 0; cnt1[g] = 0; }
  if (g < 256) { s1[g] = 0.f; s2[g] = 0.f; }
}

__global__ void fusew_kernel(const float* __restrict__ Wd0, const float* __restrict__ Ws0,
                             const float* __restrict__ Wu0,
                             const float* __restrict__ Wd1, const float* __restrict__ Ws1,
                             const float* __restrict__ Wu1,
                             unsigned short* __restrict__ Wfb, int K) {
  int gid = blockIdx.x * blockDim.x + threadIdx.x;
  int total = 192 * K;
  if (gid >= total) return;
  int i = gid / K, j = gid - i * K;
  float s = 0.f;
  if (i < 64) {
#pragma unroll 4
    for (int k = 0; k < 64; ++k)
      s += Wu0[i * 128 + k] * Wd0[k * K + j] + Wu1[i * 128 + k] * Wd1[k * K + j];
  } else if (i < 128) {
    int ii = i - 64;
#pragma unroll 4
    for (int k = 0; k < 64; ++k) s += Wu0[ii * 128 + 64 + k] * Ws0[k * K + j];
  } else {
    int ii = i - 128;
#pragma unroll 4
    for (int k = 0; k < 64; ++k) s += Wu1[ii * 128 + 64 + k] * Ws1[k * K + j];
  }
  Wfb[gid] = f2bf(0.5f * s);
}

__global__ void cvt_kernel(const float* __restrict__ x, unsigned short* __restrict__ xb,
                           int n4) {
  int g = blockIdx.x * 256 + threadIdx.x;
  if (g >= n4) return;
  f32x4 v = ((const f32x4*)x)[g];
  u16x4 o;
#pragma unroll
  for (int j = 0; j < 4; ++j) o[j] = f2bf(v[j]);
  ((u16x4*)xb)[g] = o;
}

__global__ void count_both(const int* __restrict__ dst0, const int* __restrict__ dst1,
                           int* __restrict__ cnt0, int* __restrict__ cnt1, int E, int eg) {
  int b = blockIdx.x;
  bool t1 = b >= eg;
  int e = (t1 ? b - eg : b) * 256 + threadIdx.x;
  if (e >= E) return;
  if (t1) atomicAdd(&cnt1[dst1[e]], 1);
  else atomicAdd(&cnt0[dst0[e]], 1);
}

__global__ __launch_bounds__(1024) void scan_kernel(const int* __restrict__ cnt0,
                                                    const int* __restrict__ cnt1,
                                                    int* __restrict__ base0,
                                                    int* __restrict__ base1, int N) {
  const int nt = 1024;
  __shared__ int lds[1024];
  const int* cnt = blockIdx.x == 0 ? cnt0 : cnt1;
  int* base = blockIdx.x == 0 ? base0 : base1;
  int t = threadIdx.x;
  int chunk = (N + nt - 1) / nt;
  int s = t * chunk;
  int e = min(N, s + chunk);
  int sum = 0;
  for (int i = s; i < e; ++i) sum += cnt[i];
  lds[t] = sum;
  __syncthreads();
  for (int off = 1; off < nt; off <<= 1) {
    int v = lds[t];
    if (t >= off) v += lds[t - off];
    __syncthreads();
    lds[t] = v;
    __syncthreads();
  }
  int run = lds[t] - sum;
  for (int i = s; i < e; ++i) {
    base[i] = run;
    run += cnt[i];
  }
  if (t == nt - 1) base[N] = lds[nt - 1];
}

__global__ void fill_both(const int* __restrict__ src0, const int* __restrict__ dst0,
                          const int* __restrict__ base0, int* __restrict__ cnt0,
                          int* __restrict__ csr0,
                          const int* __restrict__ src1, const int* __restrict__ dst1,
                          const int* __restrict__ base1, int* __restrict__ cnt1,
                          int* __restrict__ csr1, int E, int eg) {
  int b = blockIdx.x;
  bool t1 = b >= eg;
  int e = (t1 ? b - eg : b) * 256 + threadIdx.x;
  if (e >= E) return;
  const int* src = t1 ? src1 : src0;
  const int* dst = t1 ? dst1 : dst0;
  const int* base = t1 ? base1 : base0;
  int* cnt = t1 ? cnt1 : cnt0;
  int* csr = t1 ? csr1 : csr0;
  int d = dst[e];
  int p = atomicSub(&cnt[d], 1) - 1;
  csr[base[d] + p] = src[e];
}

// [h|P0|P1] = xb[N,K](bf16) @ Wfb[192,K]^T(bf16). 64 rows/block, 4 waves x 48 cols.
// MFMA 16x16x32_bf16; B frags in registers, A frags from global (16 full lines/load).
template <int K>
__global__ __launch_bounds__(256) void mm_mfma(const unsigned short* __restrict__ xb,
                                               const unsigned short* __restrict__ Wfb,
                                               float* __restrict__ h,
                                               unsigned short* __restrict__ P0,
                                               unsigned short* __restrict__ P1, int N) {
  constexpr int NKS = K / 32;
  int tid = threadIdx.x;
  int l = tid & 63;
  int wv = tid >> 6;  // 0..3
  int lr = l & 15;    // row (A) / col (B,D) within tile
  int lj = l >> 4;    // k-group 0..3
  int brow = blockIdx.x * 64;
  int wcol = wv * 48;

  bf16x8 B[3 * NKS];
#pragma unroll
  for (int ct = 0; ct < 3; ++ct)
#pragma unroll
    for (int ks = 0; ks < NKS; ++ks) {
      int col = wcol + ct * 16 + lr;
      B[ct * NKS + ks] = *(const bf16x8*)&Wfb[(size_t)col * K + ks * 32 + lj * 8];
    }

  f32x4 acc[4][3];
#pragma unroll
  for (int rt = 0; rt < 4; ++rt)
#pragma unroll
    for (int ct = 0; ct < 3; ++ct) acc[rt][ct] = (f32x4){0.f, 0.f, 0.f, 0.f};

#pragma unroll
  for (int ks = 0; ks < NKS; ++ks) {
    bf16x8 A[4];
#pragma unroll
    for (int rt = 0; rt < 4; ++rt) {
      int row = brow + rt * 16 + lr;
      if (row >= N) row = N - 1;
      A[rt] = *(const bf16x8*)&xb[(size_t)row * K + ks * 32 + lj * 8];
    }
#pragma unroll
    for (int rt = 0; rt < 4; ++rt)
#pragma unroll
      for (int ct = 0; ct < 3; ++ct)
        acc[rt][ct] =
            __builtin_amdgcn_mfma_f32_16x16x32_bf16(A[rt], B[ct * NKS + ks], acc[rt][ct], 0, 0, 0);
  }

#pragma unroll
  for (int rt = 0; rt < 4; ++rt)
#pragma unroll
    for (int ct = 0; ct < 3; ++ct) {
      int gct = (wcol >> 4) + ct;  // 0..11
      int sel = gct >> 2;          // 0=h 1=P0 2=P1
      int c0 = (gct & 3) * 16 + lr;
#pragma unroll
      for (int r = 0; r < 4; ++r) {
        int row = brow + rt * 16 + lj * 4 + r;
        if (row < N) {
          if (sel == 0) h[(size_t)row * 64 + c0] = acc[rt][ct][r];
          else if (sel == 1) P0[(size_t)row * 64 + c0] = f2bf(acc[rt][ct][r]);
          else P1[(size_t)row * 64 + c0] = f2bf(acc[rt][ct][r]);
        }
      }
    }
}

// half-wave (32 lanes, 2 ch/lane) per dst node; bf16 gathers, fp32 accumulate.
__global__ void agg_kernel(float* __restrict__ h, const unsigned short* __restrict__ P0,
                           const unsigned short* __restrict__ P1,
                           const int* __restrict__ csr0, const int* __restrict__ base0,
                           const int* __restrict__ csr1, const int* __restrict__ base1,
                           int N) {
  int gid = blockIdx.x * blockDim.x + threadIdx.x;
  int w = gid >> 5, c = gid & 31;
  if (w >= N) return;
  float a0 = 0.f, a1 = 0.f;
  int b0 = base0[w], e0 = base0[w + 1];
  for (int i = b0; i < e0; ++i) {
    unsigned int u = *(const unsigned int*)&P0[(size_t)csr0[i] * 64 + 2 * c];
    a0 += bfl(u);
    a1 += bfh(u);
  }
  float i0 = 1.0f / fmaxf((float)(e0 - b0), 1.0f);
  float s0 = a0 * i0, s1 = a1 * i0;
  a0 = 0.f; a1 = 0.f;
  int b1 = base1[w], e1 = base1[w + 1];
  for (int i = b1; i < e1; ++i) {
    unsigned int u = *(const unsigned int*)&P1[(size_t)csr1[i] * 64 + 2 * c];
    a0 += bfl(u);
    a1 += bfh(u);
  }
  float i1 = 1.0f / fmaxf((float)(e1 - b1), 1.0f);
  s0 += a0 * i1;
  s1 += a1 * i1;
  f32x2* hp = (f32x2*)&h[(size_t)w * 64 + 2 * c];
  f32x2 hv = *hp;
  hv.x += s0;
  hv.y += s1;
  *hp = hv;
}

__global__ __launch_bounds__(256) void bnstats_kernel(const float* __restrict__ h,
                                                      float* __restrict__ stats, int N) {
  int tid = threadIdx.x;
  int c = tid & 63;
  int part = tid >> 6;
  float s = 0.f, s2 = 0.f;
  for (int r = blockIdx.x * 4 + part; r < N; r += gridDim.x * 4) {
    float v = h[(size_t)r * 64 + c];
    s += v;
    s2 += v * v;
  }
  __shared__ float red[512];
  red[tid] = s;
  red[256 + tid] = s2;
  __syncthreads();
  if (part == 0) {
    s = red[c] + red[64 + c] + red[128 + c] + red[192 + c];
    s2 = red[256 + c] + red[256 + 64 + c] + red[256 + 128 + c] + red[256 + 192 + c];
    atomicAdd(&stats[c], s);
    atomicAdd(&stats[64 + c], s2);
  }
}

__global__ void bnfinal_kernel(float* __restrict__ stats, const float* __restrict__ g,
                               const float* __restrict__ b, float invN) {
  int c = threadIdx.x;
  if (c >= 64) return;
  float m = stats[c] * invN;
  float v = stats[64 + c] * invN - m * m;
  float a = g[c] * rsqrtf(v + 1.0f);
  stats[128 + c] = a;
  stats[192 + c] = b[c] - m * a;
}

// h fp32 -> bf16 activated features for layer-2 GEMM input
__global__ void bnapply_kernel(const float* __restrict__ h, const float* __restrict__ stats,
                               unsigned short* __restrict__ xo, int N) {
  int gid = blockIdx.x * blockDim.x + threadIdx.x;
  if (gid >= N * 16) return;
  f32x4 v = ((const f32x4*)h)[gid];
  int c = (gid & 15) * 4;
  const float* a = stats + 128;
  const float* bb = stats + 192;
  u16x4 o;
#pragma unroll
  for (int j = 0; j < 4; ++j) {
    float t = fmaf(a[c + j], v[j], bb[c + j]);
    o[j] = f2bf(fmaxf(t, 0.01f * t));
  }
  ((u16x4*)xo)[gid] = o;
}

// out[row]=[x[src]||x[dst]] with BN2+leaky applied on the fly from h2 fp32.
__global__ void gather_kernel(const float* __restrict__ h2, const float* __restrict__ stats,
                              const int* __restrict__ src0, const int* __restrict__ dst0,
                              const int* __restrict__ src1, const int* __restrict__ dst1,
                              float* __restrict__ out, int E) {
  int gid = blockIdx.x * blockDim.x + threadIdx.x;
  int total = 2 * E * 32;
  if (gid >= total) return;
  int row = gid >> 5, q = gid & 31;
  int e, s, d;
  if (row < E) {
    e = row; s = src0[e]; d = dst0[e];
  } else {
    e = row - E; s = src1[e]; d = dst1[e];
  }
  int node = (q < 16) ? s : d;
  int qq = q & 15;
  f32x4 v = *(const f32x4*)&h2[(size_t)node * 64 + qq * 4];
  int c = qq * 4;
  const float* a = stats + 128;
  const float* bb = stats + 192;
  f32x4 o;
#pragma unroll
  for (int j = 0; j < 4; ++j) {
    float t = fmaf(a[c + j], v[j], bb[c + j]);
    o[j] = fmaxf(t, 0.01f * t);
  }
  __builtin_nontemporal_store(o, (f32x4*)out + gid);
}

extern "C" void kernel_launch(void* const* d_in, const int* in_sizes, int n_in,
                              void* d_out, int out_size, void* d_ws, size_t ws_size,
                              hipStream_t stream) {
  const float* x0 = (const float*)d_in[0];
  const int* ei0 = (const int*)d_in[1];
  const int* ei1 = (const int*)d_in[2];
  const float* l1t0_Wd = (const float*)d_in[3];
  const float* l1t0_Ws = (const float*)d_in[4];
  const float* l1t0_Wu = (const float*)d_in[5];
  const float* l1t1_Wd = (const float*)d_in[6];
  const float* l1t1_Ws = (const float*)d_in[7];
  const float* l1t1_Wu = (const float*)d_in[8];
  const float* l2t0_Wd = (const float*)d_in[9];
  const float* l2t0_Ws = (const float*)d_in[10];
  const float* l2t0_Wu = (const float*)d_in[11];
  const float* l2t1_Wd = (const float*)d_in[12];
  const float* l2t1_Ws = (const float*)d_in[13];
  const float* l2t1_Wu = (const float*)d_in[14];
  const float* bn1_g = (const float*)d_in[15];
  const float* bn1_b = (const float*)d_in[16];
  const float* bn2_g = (const float*)d_in[17];
  const float* bn2_b = (const float*)d_in[18];

  const int N = in_sizes[0] / 128;
  const int E = in_sizes[1] / 2;
  const int *src0 = ei0, *dst0 = ei0 + E;
  const int *src1 = ei1, *dst1 = ei1 + E;

  char* wsb = (char*)d_ws;
  size_t off = 0;
  auto alloc = [&](size_t bytes) {
    char* p = wsb + off;
    off = (off + bytes + 255) & ~(size_t)255;
    return (void*)p;
  };
  unsigned short* Wfb1 = (unsigned short*)alloc(192 * 128 * 2);
  unsigned short* Wfb2 = (unsigned short*)alloc(192 * 64 * 2);
  float* stats1 = (float*)alloc(256 * 4);
  float* stats2 = (float*)alloc(256 * 4);
  int* cnt0 = (int*)alloc((size_t)N * 4);
  int* cnt1 = (int*)alloc((size_t)N * 4);
  int* base0 = (int*)alloc(((size_t)N + 1) * 4);
  int* base1 = (int*)alloc(((size_t)N + 1) * 4);
  int* csr0 = (int*)alloc((size_t)E * 4);
  int* csr1 = (int*)alloc((size_t)E * 4);
  unsigned short* xb = (unsigned short*)alloc((size_t)N * 128 * 2);
  float* h = (float*)alloc((size_t)N * 64 * 4);
  float* h2 = (float*)alloc((size_t)N * 64 * 4);
  unsigned short* P0 = (unsigned short*)alloc((size_t)N * 64 * 2);
  unsigned short* P1 = (unsigned short*)alloc((size_t)N * 64 * 2);
  unsigned short* xcb = (unsigned short*)alloc((size_t)N * 64 * 2);

  const float invN = 1.0f / (float)N;
  const int eg = (E + 255) / 256;

  zero_kernel<<<(N + 255) / 256, 256, 0, stream>>>(cnt0, cnt1, stats1, stats2, N);
  count_both<<<2 * eg, 256, 0, stream>>>(dst0, dst1, cnt0, cnt1, E, eg);
  scan_kernel<<<2, 1024, 0, stream>>>(cnt0, cnt1, base0, base1, N);
  fill_both<<<2 * eg, 256, 0, stream>>>(src0, dst0, base0, cnt0, csr0,
                                        src1, dst1, base1, cnt1, csr1, E, eg);

  fusew_kernel<<<(192 * 128 + 255) / 256, 256, 0, stream>>>(
      l1t0_Wd, l1t0_Ws, l1t0_Wu, l1t1_Wd, l1t1_Ws, l1t1_Wu, Wfb1, 128);
  fusew_kernel<<<(192 * 64 + 255) / 256, 256, 0, stream>>>(
      l2t0_Wd, l2t0_Ws, l2t0_Wu, l2t1_Wd, l2t1_Ws, l2t1_Wu, Wfb2, 64);
  cvt_kernel<<<(N * 32 + 255) / 256, 256, 0, stream>>>(x0, xb, N * 32);

  const int mmGrid = (N + 63) / 64;
  const int aggGrid = (N * 32 + 255) / 256;

  // layer 1
  mm_mfma<128><<<mmGrid, 256, 0, stream>>>(xb, Wfb1, h, P0, P1, N);
  agg_kernel<<<aggGrid, 256, 0, stream>>>(h, P0, P1, csr0, base0, csr1, base1, N);
  bnstats_kernel<<<256, 256, 0, stream>>>(h, stats1, N);
  bnfinal_kernel<<<1, 64, 0, stream>>>(stats1, bn1_g, bn1_b, invN);
  bnapply_kernel<<<(N * 16 + 255) / 256, 256, 0, stream>>>(h, stats1, xcb, N);

  // layer 2
  mm_mfma<64><<<mmGrid, 256, 0, stream>>>(xcb, Wfb2, h2, P0, P1, N);
  agg_kernel<<<aggGrid, 256, 0, stream>>>(h2, P0, P1, csr0, base0, csr1, base1, N);
  bnstats_kernel<<<256, 256, 0, stream>>>(h2, stats2, N);
  bnfinal_kernel<<<1, 64, 0, stream>>>(stats2, bn2_g, bn2_b, invN);

  // output gather with BN2 + leaky fused
  gather_kernel<<<(2 * E * 32 + 255) / 256, 256, 0, stream>>>(
      h2, stats2, src0, dst0, src1, dst1, (float*)d_out, E);
}